// Round 1
// baseline (1117.360 us; speedup 1.0000x reference)
//
#include <hip/hip_runtime.h>

// GCN link-prediction pipeline, N=1M nodes, D=16 feats, E=5M edges, EL=2M pairs.
// Factorization per GCNConv layer:
//   g[i]   = (h[i] @ W) * dinv[i]                (dense, per-node)
//   acc[d] = g[d] + sum_{edges (s,d)} g[s]       (copy-init + atomic scatter)
//   out[d] = dinv[d] * acc[d] + b                (finalize)

__global__ __launch_bounds__(256) void deg_kernel(
    const int* __restrict__ dst, float* __restrict__ deg, int E) {
  int e = blockIdx.x * 256 + threadIdx.x;
  if (e < E) atomicAdd(&deg[dst[e]], 1.0f);
}

__global__ __launch_bounds__(256) void dinv_kernel(float* __restrict__ deg, int n) {
  int i = blockIdx.x * 256 + threadIdx.x;
  if (i < n) deg[i] = rsqrtf(deg[i] + 1.0f);  // +1 = self loop
}

// g[i,:] = (embed[x[i],:] @ W) * dinv[i]   (W is 16x16 row-major in LDS)
__global__ __launch_bounds__(256) void embed_mm_kernel(
    const int* __restrict__ x, const float* __restrict__ embed,
    const float* __restrict__ W, const float* __restrict__ dinv,
    float* __restrict__ g, int n) {
  __shared__ float Ws[256];
  Ws[threadIdx.x] = W[threadIdx.x];
  __syncthreads();
  int i = blockIdx.x * 256 + threadIdx.x;
  if (i >= n) return;
  int row = x[i];
  const float4* hp = (const float4*)(embed + (size_t)row * 16);
  float4 a = hp[0], b = hp[1], c = hp[2], d = hp[3];
  float h[16] = {a.x,a.y,a.z,a.w, b.x,b.y,b.z,b.w,
                 c.x,c.y,c.z,c.w, d.x,d.y,d.z,d.w};
  float o[16];
#pragma unroll
  for (int j = 0; j < 16; ++j) o[j] = 0.f;
#pragma unroll
  for (int k = 0; k < 16; ++k) {
    float hk = h[k];
#pragma unroll
    for (int j = 0; j < 16; ++j) o[j] = fmaf(hk, Ws[k * 16 + j], o[j]);
  }
  float dv = dinv[i];
  float4* op = (float4*)(g + (size_t)i * 16);
  op[0] = make_float4(o[0]*dv,  o[1]*dv,  o[2]*dv,  o[3]*dv);
  op[1] = make_float4(o[4]*dv,  o[5]*dv,  o[6]*dv,  o[7]*dv);
  op[2] = make_float4(o[8]*dv,  o[9]*dv,  o[10]*dv, o[11]*dv);
  op[3] = make_float4(o[12]*dv, o[13]*dv, o[14]*dv, o[15]*dv);
}

// acc = g (self-loop term doubles as zero-init; ws is poisoned every launch)
__global__ __launch_bounds__(256) void copy_kernel(
    const float4* __restrict__ in, float4* __restrict__ out, int n4) {
  int i = blockIdx.x * 256 + threadIdx.x;
  if (i < n4) out[i] = in[i];
}

// 16 threads per edge: acc[dst,f] += g[src,f]
__global__ __launch_bounds__(256) void scatter_kernel(
    const int* __restrict__ src, const int* __restrict__ dst,
    const float* __restrict__ g, float* __restrict__ acc, int E) {
  int tid = blockIdx.x * 256 + threadIdx.x;
  int e = tid >> 4;
  if (e >= E) return;
  int f = tid & 15;
  int s = src[e], d = dst[e];
  atomicAdd(&acc[(size_t)d * 16 + f], g[(size_t)s * 16 + f]);
}

// h = relu(dinv*acc + b1); g2 = (h @ W2) * dinv   (fused layer-1 finalize + layer-2 GEMM)
__global__ __launch_bounds__(256) void fin_relu_mm_kernel(
    const float* __restrict__ acc, const float* __restrict__ dinv,
    const float* __restrict__ bias, const float* __restrict__ W,
    float* __restrict__ g2, int n) {
  __shared__ float Ws[256];
  __shared__ float bs[16];
  Ws[threadIdx.x] = W[threadIdx.x];
  if (threadIdx.x < 16) bs[threadIdx.x] = bias[threadIdx.x];
  __syncthreads();
  int i = blockIdx.x * 256 + threadIdx.x;
  if (i >= n) return;
  float dv = dinv[i];
  const float4* ap = (const float4*)(acc + (size_t)i * 16);
  float4 a = ap[0], b = ap[1], c = ap[2], d = ap[3];
  float h[16] = {a.x,a.y,a.z,a.w, b.x,b.y,b.z,b.w,
                 c.x,c.y,c.z,c.w, d.x,d.y,d.z,d.w};
#pragma unroll
  for (int k = 0; k < 16; ++k) h[k] = fmaxf(fmaf(dv, h[k], bs[k]), 0.f);
  float o[16];
#pragma unroll
  for (int j = 0; j < 16; ++j) o[j] = 0.f;
#pragma unroll
  for (int k = 0; k < 16; ++k) {
    float hk = h[k];
#pragma unroll
    for (int j = 0; j < 16; ++j) o[j] = fmaf(hk, Ws[k * 16 + j], o[j]);
  }
  float4* op = (float4*)(g2 + (size_t)i * 16);
  op[0] = make_float4(o[0]*dv,  o[1]*dv,  o[2]*dv,  o[3]*dv);
  op[1] = make_float4(o[4]*dv,  o[5]*dv,  o[6]*dv,  o[7]*dv);
  op[2] = make_float4(o[8]*dv,  o[9]*dv,  o[10]*dv, o[11]*dv);
  op[3] = make_float4(o[12]*dv, o[13]*dv, o[14]*dv, o[15]*dv);
}

// z = dinv*acc + b2
__global__ __launch_bounds__(256) void fin2_kernel(
    const float* __restrict__ acc, const float* __restrict__ dinv,
    const float* __restrict__ bias, float* __restrict__ z, int n) {
  __shared__ float bs[16];
  if (threadIdx.x < 16) bs[threadIdx.x] = bias[threadIdx.x];
  __syncthreads();
  int i = blockIdx.x * 256 + threadIdx.x;
  if (i >= n) return;
  float dv = dinv[i];
  const float4* ap = (const float4*)(acc + (size_t)i * 16);
  float4 a = ap[0], b = ap[1], c = ap[2], d = ap[3];
  float4* op = (float4*)(z + (size_t)i * 16);
  op[0] = make_float4(fmaf(dv,a.x,bs[0]),  fmaf(dv,a.y,bs[1]),  fmaf(dv,a.z,bs[2]),  fmaf(dv,a.w,bs[3]));
  op[1] = make_float4(fmaf(dv,b.x,bs[4]),  fmaf(dv,b.y,bs[5]),  fmaf(dv,b.z,bs[6]),  fmaf(dv,b.w,bs[7]));
  op[2] = make_float4(fmaf(dv,c.x,bs[8]),  fmaf(dv,c.y,bs[9]),  fmaf(dv,c.z,bs[10]), fmaf(dv,c.w,bs[11]));
  op[3] = make_float4(fmaf(dv,d.x,bs[12]), fmaf(dv,d.y,bs[13]), fmaf(dv,d.z,bs[14]), fmaf(dv,d.w,bs[15]));
}

// out[e] = [z[a], z[b]] . fc_w + fc_b
__global__ __launch_bounds__(256) void predict_kernel(
    const int* __restrict__ eli, const float* __restrict__ z,
    const float* __restrict__ fcw, const float* __restrict__ fcb,
    float* __restrict__ out, int EL) {
  __shared__ float w[32];
  __shared__ float bb;
  if (threadIdx.x < 32) w[threadIdx.x] = fcw[threadIdx.x];
  if (threadIdx.x == 0) bb = fcb[0];
  __syncthreads();
  int e = blockIdx.x * 256 + threadIdx.x;
  if (e >= EL) return;
  int a = eli[e], b = eli[EL + e];
  const float4* za = (const float4*)(z + (size_t)a * 16);
  const float4* zb = (const float4*)(z + (size_t)b * 16);
  float s = bb;
  float4 v;
  v = za[0]; s += v.x*w[0]  + v.y*w[1]  + v.z*w[2]  + v.w*w[3];
  v = za[1]; s += v.x*w[4]  + v.y*w[5]  + v.z*w[6]  + v.w*w[7];
  v = za[2]; s += v.x*w[8]  + v.y*w[9]  + v.z*w[10] + v.w*w[11];
  v = za[3]; s += v.x*w[12] + v.y*w[13] + v.z*w[14] + v.w*w[15];
  v = zb[0]; s += v.x*w[16] + v.y*w[17] + v.z*w[18] + v.w*w[19];
  v = zb[1]; s += v.x*w[20] + v.y*w[21] + v.z*w[22] + v.w*w[23];
  v = zb[2]; s += v.x*w[24] + v.y*w[25] + v.z*w[26] + v.w*w[27];
  v = zb[3]; s += v.x*w[28] + v.y*w[29] + v.z*w[30] + v.w*w[31];
  out[e] = s;
}

static inline int cdiv(long long a, long long b) { return (int)((a + b - 1) / b); }

extern "C" void kernel_launch(void* const* d_in, const int* in_sizes, int n_in,
                              void* d_out, int out_size, void* d_ws, size_t ws_size,
                              hipStream_t stream) {
  const int*   x     = (const int*)d_in[0];
  const int*   ei    = (const int*)d_in[1];   // [2,E] row-major: src=ei[0:E), dst=ei[E:2E)
  const int*   eli   = (const int*)d_in[2];   // [2,EL]
  const float* embed = (const float*)d_in[3];
  const float* W1    = (const float*)d_in[4];
  const float* b1    = (const float*)d_in[5];
  const float* W2    = (const float*)d_in[6];
  const float* b2    = (const float*)d_in[7];
  const float* fcw   = (const float*)d_in[8];
  const float* fcb   = (const float*)d_in[9];
  float* out = (float*)d_out;

  const int N  = in_sizes[0];
  const int E  = in_sizes[1] / 2;
  const int EL = in_sizes[2] / 2;
  const int*   src = ei;
  const int*   dst = ei + E;

  // workspace layout: dinv [N] | bufA [N*16] | bufB [N*16]  (fp32) = 132 MB
  char* ws = (char*)d_ws;
  float* dinv = (float*)ws;
  float* bufA = (float*)(ws + (size_t)N * 4);
  float* bufB = (float*)(ws + (size_t)N * 4 + (size_t)N * 64);

  const int B = 256;
  int n4 = N * 4;  // float4 count of an N x 16 buffer

  // degree + dinv (ws is poisoned each launch -> must zero)
  hipMemsetAsync(dinv, 0, (size_t)N * 4, stream);
  deg_kernel<<<cdiv(E, B), B, 0, stream>>>(dst, dinv, E);
  dinv_kernel<<<cdiv(N, B), B, 0, stream>>>(dinv, N);

  // layer 1: g1 = (embed[x] @ W1) * dinv  -> bufA
  embed_mm_kernel<<<cdiv(N, B), B, 0, stream>>>(x, embed, W1, dinv, bufA, N);
  // acc1 = g1 (self loop + init) -> bufB ; scatter edges
  copy_kernel<<<cdiv(n4, B), B, 0, stream>>>((const float4*)bufA, (float4*)bufB, n4);
  scatter_kernel<<<cdiv((long long)E * 16, B), B, 0, stream>>>(src, dst, bufA, bufB, E);
  // h1 = relu(dinv*acc1 + b1); g2 = (h1 @ W2) * dinv -> bufA
  fin_relu_mm_kernel<<<cdiv(N, B), B, 0, stream>>>(bufB, dinv, b1, W2, bufA, N);

  // layer 2: acc2 = g2 ; scatter ; z = dinv*acc2 + b2
  copy_kernel<<<cdiv(n4, B), B, 0, stream>>>((const float4*)bufA, (float4*)bufB, n4);
  scatter_kernel<<<cdiv((long long)E * 16, B), B, 0, stream>>>(src, dst, bufA, bufB, E);
  fin2_kernel<<<cdiv(N, B), B, 0, stream>>>(bufB, dinv, b2, bufA, N);  // z -> bufA

  // link prediction
  predict_kernel<<<cdiv(EL, B), B, 0, stream>>>(eli, bufA, fcw, fcb, out, EL);
}